// Round 2
// baseline (1007.420 us; speedup 1.0000x reference)
//
#include <hip/hip_runtime.h>

#define TPB 256
constexpr int HID = 16;
constexpr int NC  = 8;

__device__ __forceinline__ void atomAddF(float* p, float v) {
    unsafeAtomicAdd(p, v);   // native global_atomic_add_f32
}

// Detect whether edge_index arrived as int64 (odd 32-bit words all zero) or int32.
__global__ void detect64_kernel(const int* __restrict__ ei, int E, int* flag) {
    int l = threadIdx.x;
    int v = 0;
    if (l < 32 && 2 * l + 1 < 2 * E) v = ei[2 * l + 1];
    unsigned long long b = __ballot(v != 0);
    if (l == 0) *flag = (b == 0ULL) ? 1 : 0;
}

__device__ __forceinline__ int edge_at(const int* __restrict__ ei, int index, int is64) {
    return is64 ? ei[2 * index] : ei[index];
}

// deg[i]=1.0 (self loop), cnt[i]=0
__global__ void initdc_kernel(float* deg, int* cnt, int N) {
    int i = blockIdx.x * TPB + threadIdx.x;
    if (i < N) { deg[i] = 1.0f; cnt[i] = 0; }
}

// weighted degree + integer histogram of dst
__global__ void histo_kernel(const int* __restrict__ ei, const float* __restrict__ w,
                             float* deg, int* cnt, int E, const int* __restrict__ flag) {
    int e = blockIdx.x * TPB + threadIdx.x;
    if (e >= E) return;
    int is64 = *flag;
    int dst = edge_at(ei, E + e, is64);
    atomicAdd(&cnt[dst], 1);
    atomAddF(&deg[dst], w[e]);
}

__global__ void dis_kernel(float* deg, int N) {
    int i = blockIdx.x * TPB + threadIdx.x;
    if (i < N) deg[i] = rsqrtf(deg[i]);   // deg >= 1 always
}

// ---------------- exclusive scan of cnt -> rowptr (3 kernels) ----------------
// chunk = 1024 per block (256 threads x 4)
__global__ void scan1_kernel(const int* __restrict__ cnt, int* bsum, int N) {
    __shared__ int sd[256];
    int t = threadIdx.x;
    int base = blockIdx.x * 1024 + t * 4;
    int s = 0;
#pragma unroll
    for (int q = 0; q < 4; ++q) if (base + q < N) s += cnt[base + q];
    sd[t] = s; __syncthreads();
    for (int off = 128; off >= 1; off >>= 1) {
        if (t < off) sd[t] += sd[t + off];
        __syncthreads();
    }
    if (t == 0) bsum[blockIdx.x] = sd[0];
}

__global__ void scan2_kernel(int* bsum, int nb) {
    if (threadIdx.x == 0) {
        int a = 0;
        for (int i = 0; i < nb; ++i) { int v = bsum[i]; bsum[i] = a; a += v; }
    }
}

__global__ void scan3_kernel(const int* __restrict__ cnt, const int* __restrict__ bsum,
                             int* rowptr, int* next, int N) {
    __shared__ int sd[256];
    int t = threadIdx.x;
    int base = blockIdx.x * 1024 + t * 4;
    int v0 = 0, v1 = 0, v2 = 0, v3 = 0;
    if (base + 0 < N) v0 = cnt[base + 0];
    if (base + 1 < N) v1 = cnt[base + 1];
    if (base + 2 < N) v2 = cnt[base + 2];
    if (base + 3 < N) v3 = cnt[base + 3];
    int s = v0 + v1 + v2 + v3;
    sd[t] = s; __syncthreads();
    for (int off = 1; off < 256; off <<= 1) {
        int val = 0;
        if (t >= off) val = sd[t - off];
        __syncthreads();
        if (t >= off) sd[t] += val;
        __syncthreads();
    }
    int excl = sd[t] - s + bsum[blockIdx.x];
    int e0 = excl, e1 = e0 + v0, e2 = e1 + v1, e3 = e2 + v2;
    if (base + 0 < N) { rowptr[base + 0] = e0; next[base + 0] = e0; }
    if (base + 1 < N) { rowptr[base + 1] = e1; next[base + 1] = e1; }
    if (base + 2 < N) { rowptr[base + 2] = e2; next[base + 2] = e2; }
    if (base + 3 < N) { rowptr[base + 3] = e3; next[base + 3] = e3; }
}

// scatter edges into dst-sorted CSR order: srcs[p], nrmv[p]
__global__ void scatter_kernel(const int* __restrict__ ei, const float* __restrict__ w,
                               const float* __restrict__ dis, int* next,
                               int* __restrict__ srcs, float* __restrict__ nrmv,
                               int E, const int* __restrict__ flag) {
    int e = blockIdx.x * TPB + threadIdx.x;
    if (e >= E) return;
    int is64 = *flag;
    int src = edge_at(ei, e, is64);
    int dst = edge_at(ei, E + e, is64);
    float nrm = dis[src] * w[e] * dis[dst];
    int p = atomicAdd(&next[dst], 1);
    srcs[p] = src;
    nrmv[p] = nrm;
}

// ---------------- gemm1: h1 = x @ W1, LDS-tiled coalesced ----------------
constexpr int GR  = 256;  // rows per block
constexpr int KT  = 32;   // k tile
constexpr int LDP = 33;   // padded LDS stride (conflict-free b32 reads)
__global__ __launch_bounds__(256) void gemm1_kernel(const float* __restrict__ x,
                                                    const float* __restrict__ W,
                                                    float* __restrict__ h, int N, int K) {
    __shared__ float tile[GR * LDP];
    int t = threadIdx.x;
    int row0 = blockIdx.x * GR;
    float acc[HID];
#pragma unroll
    for (int j = 0; j < HID; ++j) acc[j] = 0.f;
    for (int kt = 0; kt < K; kt += KT) {
        __syncthreads();
#pragma unroll
        for (int q = 0; q < 8; ++q) {
            int f  = q * 256 + t;       // flat float4 index in 256x32 tile
            int r  = f >> 3;            // 8 float4 per row
            int c4 = f & 7;
            int gr = row0 + r;
            if (gr > N - 1) gr = N - 1;
            float4 v = *reinterpret_cast<const float4*>(x + (size_t)gr * K + kt + c4 * 4);
            float* dstp = &tile[r * LDP + c4 * 4];
            dstp[0] = v.x; dstp[1] = v.y; dstp[2] = v.z; dstp[3] = v.w;
        }
        __syncthreads();
        const float* Wk = W + (size_t)kt * HID;
        const float* lr = &tile[t * LDP];
#pragma unroll
        for (int k = 0; k < KT; ++k) {
            float a = lr[k];
#pragma unroll
            for (int j = 0; j < HID; ++j)
                acc[j] = fmaf(a, Wk[k * HID + j], acc[j]);
        }
    }
    int row = row0 + t;
    if (row < N) {
        float* hr = h + (size_t)row * HID;
#pragma unroll
        for (int j = 0; j < HID; j += 4)
            *reinterpret_cast<float4*>(hr + j) = make_float4(acc[j], acc[j+1], acc[j+2], acc[j+3]);
    }
}

// pull aggregation layer 1: 16 lanes per node, no atomics; fuses self-loop + bias
__global__ void pull1_kernel(const int* __restrict__ rowptr, const int* __restrict__ cnt,
                             const int* __restrict__ srcs, const float* __restrict__ nrmv,
                             const float* __restrict__ h1, const float* __restrict__ dis,
                             const float* __restrict__ b1, float* __restrict__ agg1, int N) {
    int t = blockIdx.x * TPB + threadIdx.x;
    int i = t >> 4, j = t & 15;
    if (i >= N) return;
    int beg = rowptr[i], end = beg + cnt[i];
    float acc = 0.f;
    for (int p = beg; p < end; ++p) {
        int s = srcs[p];
        acc = fmaf(nrmv[p], h1[s * HID + j], acc);
    }
    float d = dis[i];
    agg1[t] = b1[j] + d * d * h1[i * HID + j] + acc;
}

// h2 = relu(agg1) @ W2
__global__ void gemm2_kernel(const float* __restrict__ agg1, const float* __restrict__ W2,
                             float* __restrict__ h2, int N) {
    int i = blockIdx.x * TPB + threadIdx.x;
    if (i >= N) return;
    const float* a = agg1 + (size_t)i * HID;
    float hv[HID];
#pragma unroll
    for (int k = 0; k < HID; k += 4) {
        float4 v = *reinterpret_cast<const float4*>(a + k);
        hv[k]     = fmaxf(v.x, 0.f);
        hv[k + 1] = fmaxf(v.y, 0.f);
        hv[k + 2] = fmaxf(v.z, 0.f);
        hv[k + 3] = fmaxf(v.w, 0.f);
    }
    float acc[NC];
#pragma unroll
    for (int c = 0; c < NC; ++c) acc[c] = 0.f;
#pragma unroll
    for (int k = 0; k < HID; ++k)
#pragma unroll
        for (int c = 0; c < NC; ++c)
            acc[c] = fmaf(hv[k], W2[k * NC + c], acc[c]);
    float* o = h2 + (size_t)i * NC;
    *reinterpret_cast<float4*>(o)     = make_float4(acc[0], acc[1], acc[2], acc[3]);
    *reinterpret_cast<float4*>(o + 4) = make_float4(acc[4], acc[5], acc[6], acc[7]);
}

// pull layer 2 (8 lanes/node) + fused log_softmax via width-8 shuffles
__global__ void pull2_kernel(const int* __restrict__ rowptr, const int* __restrict__ cnt,
                             const int* __restrict__ srcs, const float* __restrict__ nrmv,
                             const float* __restrict__ h2, const float* __restrict__ dis,
                             const float* __restrict__ b2, float* __restrict__ out, int N) {
    int t = blockIdx.x * TPB + threadIdx.x;
    int i = t >> 3, j = t & 7;
    if (i >= N) return;
    int beg = rowptr[i], end = beg + cnt[i];
    float acc = 0.f;
    for (int p = beg; p < end; ++p) {
        int s = srcs[p];
        acc = fmaf(nrmv[p], h2[s * NC + j], acc);
    }
    float d = dis[i];
    float v = b2[j] + d * d * h2[i * NC + j] + acc;
    float m = v;
#pragma unroll
    for (int mask = 1; mask < 8; mask <<= 1) m = fmaxf(m, __shfl_xor(m, mask, 8));
    float s8 = __expf(v - m);
#pragma unroll
    for (int mask = 1; mask < 8; mask <<= 1) s8 += __shfl_xor(s8, mask, 8);
    out[t] = v - m - __logf(s8);
}

// ---------------- fallback push-atomic kernels (used only if ws too small) ----------------
__global__ void init_agg1_kernel(const float* __restrict__ h1, const float* __restrict__ dis,
                                 const float* __restrict__ b1, float* __restrict__ agg1, int N) {
    int t = blockIdx.x * TPB + threadIdx.x;
    if (t >= N * HID) return;
    int i = t >> 4, j = t & 15;
    float d = dis[i];
    agg1[t] = b1[j] + d * d * h1[t];
}
__global__ void edge1_kernel(const int* __restrict__ ei, const float* __restrict__ w,
                             const float* __restrict__ dis, const float* __restrict__ h1,
                             float* __restrict__ agg1, int E, const int* __restrict__ flag) {
    int t = blockIdx.x * TPB + threadIdx.x;
    if (t >= E * HID) return;
    int e = t >> 4, j = t & 15;
    int is64 = *flag;
    int src = edge_at(ei, e, is64);
    int dst = edge_at(ei, E + e, is64);
    float nrm = dis[src] * w[e] * dis[dst];
    atomAddF(&agg1[dst * HID + j], nrm * h1[src * HID + j]);
}
__global__ void init_out_kernel(const float* __restrict__ h2, const float* __restrict__ dis,
                                const float* __restrict__ b2, float* __restrict__ out, int N) {
    int t = blockIdx.x * TPB + threadIdx.x;
    if (t >= N * NC) return;
    int i = t >> 3, j = t & 7;
    float d = dis[i];
    out[t] = b2[j] + d * d * h2[t];
}
__global__ void edge2_kernel(const int* __restrict__ ei, const float* __restrict__ w,
                             const float* __restrict__ dis, const float* __restrict__ h2,
                             float* __restrict__ out, int E, const int* __restrict__ flag) {
    int t = blockIdx.x * TPB + threadIdx.x;
    if (t >= E * NC) return;
    int e = t >> 3, j = t & 7;
    int is64 = *flag;
    int src = edge_at(ei, e, is64);
    int dst = edge_at(ei, E + e, is64);
    float nrm = dis[src] * w[e] * dis[dst];
    atomAddF(&out[dst * NC + j], nrm * h2[src * NC + j]);
}
__global__ void lsm_kernel(float* __restrict__ out, int N) {
    int i = blockIdx.x * TPB + threadIdx.x;
    if (i >= N) return;
    float* r = out + (size_t)i * NC;
    float4 a = *reinterpret_cast<const float4*>(r);
    float4 b = *reinterpret_cast<const float4*>(r + 4);
    float v[NC] = {a.x, a.y, a.z, a.w, b.x, b.y, b.z, b.w};
    float m = v[0];
#pragma unroll
    for (int j = 1; j < NC; ++j) m = fmaxf(m, v[j]);
    float s = 0.f;
#pragma unroll
    for (int j = 0; j < NC; ++j) s += expf(v[j] - m);
    float lse = m + logf(s);
#pragma unroll
    for (int j = 0; j < NC; ++j) v[j] -= lse;
    *reinterpret_cast<float4*>(r)     = make_float4(v[0], v[1], v[2], v[3]);
    *reinterpret_cast<float4*>(r + 4) = make_float4(v[4], v[5], v[6], v[7]);
}

extern "C" void kernel_launch(void* const* d_in, const int* in_sizes, int n_in,
                              void* d_out, int out_size, void* d_ws, size_t ws_size,
                              hipStream_t stream) {
    const float* x  = (const float*)d_in[0];
    const int*   ei = (const int*)d_in[1];
    const float* w  = (const float*)d_in[2];
    const float* W1 = (const float*)d_in[3];
    const float* b1 = (const float*)d_in[4];
    const float* W2 = (const float*)d_in[5];
    const float* b2 = (const float*)d_in[6];
    float* out = (float*)d_out;

    int E = in_sizes[2];          // 3,200,000
    int N = out_size / NC;        // 100,000
    int K = in_sizes[0] / N;      // 512

    // workspace layout
    float* deg  = (float*)d_ws;                       // N (-> dis in place)
    float* h1   = deg + N;                            // 16N
    float* agg1 = h1 + (size_t)N * HID;               // 16N
    float* h2   = agg1 + (size_t)N * HID;             // 8N
    int*   cnt    = (int*)(h2 + (size_t)N * NC);      // N
    int*   rowptr = cnt + N;                          // N
    int*   next   = rowptr + N;                       // N
    int*   srcs   = next + N;                         // E
    float* nrmv   = (float*)(srcs + E);               // E
    int*   bsum   = (int*)(nrmv + E);                 // 256
    int*   flag   = bsum + 256;                       // 1

    size_t need = ((size_t)N * (1 + 16 + 16 + 8 + 3) + 2 * (size_t)E + 257) * 4;

    auto nb = [](long long n) { return (int)((n + TPB - 1) / TPB); };

    if (ws_size >= need) {
        int nblk = (N + 1023) / 1024;
        detect64_kernel<<<1, 64, 0, stream>>>(ei, E, flag);
        initdc_kernel<<<nb(N), TPB, 0, stream>>>(deg, cnt, N);
        histo_kernel<<<nb(E), TPB, 0, stream>>>(ei, w, deg, cnt, E, flag);
        dis_kernel<<<nb(N), TPB, 0, stream>>>(deg, N);
        scan1_kernel<<<nblk, 256, 0, stream>>>(cnt, bsum, N);
        scan2_kernel<<<1, 64, 0, stream>>>(bsum, nblk);
        scan3_kernel<<<nblk, 256, 0, stream>>>(cnt, bsum, rowptr, next, N);
        scatter_kernel<<<nb(E), TPB, 0, stream>>>(ei, w, deg, next, srcs, nrmv, E, flag);
        gemm1_kernel<<<(N + GR - 1) / GR, 256, 0, stream>>>(x, W1, h1, N, K);
        pull1_kernel<<<nb((long long)N * HID), TPB, 0, stream>>>(rowptr, cnt, srcs, nrmv, h1, deg, b1, agg1, N);
        gemm2_kernel<<<nb(N), TPB, 0, stream>>>(agg1, W2, h2, N);
        pull2_kernel<<<nb((long long)N * NC), TPB, 0, stream>>>(rowptr, cnt, srcs, nrmv, h2, deg, b2, out, N);
    } else {
        // fallback: push atomics (round-1 structure)
        detect64_kernel<<<1, 64, 0, stream>>>(ei, E, flag);
        initdc_kernel<<<nb(N), TPB, 0, stream>>>(deg, cnt, N);
        histo_kernel<<<nb(E), TPB, 0, stream>>>(ei, w, deg, cnt, E, flag);
        dis_kernel<<<nb(N), TPB, 0, stream>>>(deg, N);
        gemm1_kernel<<<(N + GR - 1) / GR, 256, 0, stream>>>(x, W1, h1, N, K);
        init_agg1_kernel<<<nb((long long)N * HID), TPB, 0, stream>>>(h1, deg, b1, agg1, N);
        edge1_kernel<<<nb((long long)E * HID), TPB, 0, stream>>>(ei, w, deg, h1, agg1, E, flag);
        gemm2_kernel<<<nb(N), TPB, 0, stream>>>(agg1, W2, h2, N);
        init_out_kernel<<<nb((long long)N * NC), TPB, 0, stream>>>(h2, deg, b2, out, N);
        edge2_kernel<<<nb((long long)E * NC), TPB, 0, stream>>>(ei, w, deg, h2, out, E, flag);
        lsm_kernel<<<nb(N), TPB, 0, stream>>>(out, N);
    }
}

// Round 3
// 996.973 us; speedup vs baseline: 1.0105x; 1.0105x over previous
//
#include <hip/hip_runtime.h>

#define TPB 256
constexpr int HID = 16;
constexpr int NC  = 8;
constexpr int B3  = 256;      // blocks for edge-chunk passes
constexpr int BSH = 7;        // 128 nodes per bucket
constexpr int BNODES = 128;
constexpr int NBMAX = 1024;   // max buckets (N <= 131072)

__device__ __forceinline__ void atomAddF(float* p, float v) {
    unsafeAtomicAdd(p, v);
}

// Detect whether edge_index arrived as int64 (odd 32-bit words all zero) or int32.
__global__ void detect64_kernel(const int* __restrict__ ei, int E, int* flag) {
    int l = threadIdx.x;
    int v = 0;
    if (l < 32 && 2 * l + 1 < 2 * E) v = ei[2 * l + 1];
    unsigned long long b = __ballot(v != 0);
    if (l == 0) *flag = (b == 0ULL) ? 1 : 0;
}

__device__ __forceinline__ int edge_at(const int* __restrict__ ei, int index, int is64) {
    return is64 ? ei[2 * index] : ei[index];
}

// ---------------- P1: per-(bucket,block) edge counts via LDS histogram ----------------
__global__ __launch_bounds__(TPB) void p1_count_kernel(const int* __restrict__ ei, int* __restrict__ cnts,
                                                       int E, int NB, const int* __restrict__ flag) {
    __shared__ int h[NBMAX];
    int t = threadIdx.x;
    for (int i = t; i < NB; i += TPB) h[i] = 0;
    __syncthreads();
    int is64 = *flag;
    int chunk = (E + B3 - 1) / B3;
    int beg = blockIdx.x * chunk;
    int end = min(E, beg + chunk);
    for (int e = beg + t; e < end; e += TPB) {
        int dst = edge_at(ei, E + e, is64);
        atomicAdd(&h[dst >> BSH], 1);   // LDS atomic
    }
    __syncthreads();
    for (int i = t; i < NB; i += TPB) cnts[i * B3 + blockIdx.x] = h[i];
}

// ---------------- exclusive scan of M counts ----------------
__global__ void scan1_kernel(const int* __restrict__ a, int* bsum, int M) {
    __shared__ int sd[256];
    int t = threadIdx.x;
    int base = blockIdx.x * 1024 + t * 4;
    int s = 0;
#pragma unroll
    for (int q = 0; q < 4; ++q) if (base + q < M) s += a[base + q];
    sd[t] = s; __syncthreads();
    for (int off = 128; off >= 1; off >>= 1) {
        if (t < off) sd[t] += sd[t + off];
        __syncthreads();
    }
    if (t == 0) bsum[blockIdx.x] = sd[0];
}

// single-block parallel exclusive scan of bsum[0..nb)
__global__ void scan2_kernel(int* bsum, int nb) {
    __shared__ int sd[256];
    int t = threadIdx.x;
    int base = t * 4;
    int v0 = base + 0 < nb ? bsum[base + 0] : 0;
    int v1 = base + 1 < nb ? bsum[base + 1] : 0;
    int v2 = base + 2 < nb ? bsum[base + 2] : 0;
    int v3 = base + 3 < nb ? bsum[base + 3] : 0;
    int s = v0 + v1 + v2 + v3;
    sd[t] = s; __syncthreads();
    for (int off = 1; off < 256; off <<= 1) {
        int val = 0;
        if (t >= off) val = sd[t - off];
        __syncthreads();
        if (t >= off) sd[t] += val;
        __syncthreads();
    }
    int e = sd[t] - s;
    if (base + 0 < nb) bsum[base + 0] = e;           e += v0;
    if (base + 1 < nb) bsum[base + 1] = e;           e += v1;
    if (base + 2 < nb) bsum[base + 2] = e;           e += v2;
    if (base + 3 < nb) bsum[base + 3] = e;
}

// in-place: a[i] -> exclusive prefix
__global__ void scan3_kernel(int* a, const int* __restrict__ bsum, int M) {
    __shared__ int sd[256];
    int t = threadIdx.x;
    int base = blockIdx.x * 1024 + t * 4;
    int v0 = 0, v1 = 0, v2 = 0, v3 = 0;
    if (base + 0 < M) v0 = a[base + 0];
    if (base + 1 < M) v1 = a[base + 1];
    if (base + 2 < M) v2 = a[base + 2];
    if (base + 3 < M) v3 = a[base + 3];
    int s = v0 + v1 + v2 + v3;
    sd[t] = s; __syncthreads();
    for (int off = 1; off < 256; off <<= 1) {
        int val = 0;
        if (t >= off) val = sd[t - off];
        __syncthreads();
        if (t >= off) sd[t] += val;
        __syncthreads();
    }
    int excl = sd[t] - s + bsum[blockIdx.x];
    int e0 = excl, e1 = e0 + v0, e2 = e1 + v1, e3 = e2 + v2;
    if (base + 0 < M) a[base + 0] = e0;
    if (base + 1 < M) a[base + 1] = e1;
    if (base + 2 < M) a[base + 2] = e2;
    if (base + 3 < M) a[base + 3] = e3;
}

// ---------------- P3: scatter edges into bucket-major segments (LDS cursors) ----------------
__global__ __launch_bounds__(TPB) void p3_scatter_kernel(const int* __restrict__ ei, const float* __restrict__ w,
                                                         const int* __restrict__ scn, int2* __restrict__ payload,
                                                         int E, int NB, const int* __restrict__ flag) {
    __shared__ int cur[NBMAX];
    int t = threadIdx.x;
    for (int i = t; i < NB; i += TPB) cur[i] = scn[i * B3 + blockIdx.x];
    __syncthreads();
    int is64 = *flag;
    int chunk = (E + B3 - 1) / B3;
    int beg = blockIdx.x * chunk;
    int end = min(E, beg + chunk);
    for (int e = beg + t; e < end; e += TPB) {
        int src = edge_at(ei, e, is64);
        int dst = edge_at(ei, E + e, is64);
        int b = dst >> BSH;
        int p = atomicAdd(&cur[b], 1);   // LDS atomic
        payload[p] = make_int2(src | ((dst & (BNODES - 1)) << 20), __float_as_int(w[e]));
    }
}

// ---------------- P4: per-bucket weighted degree -> dis, all in LDS ----------------
__global__ __launch_bounds__(BNODES) void p4_deg_kernel(const int2* __restrict__ payload,
                                                        const int* __restrict__ scn,
                                                        float* __restrict__ dis, int E, int N, int NB) {
    __shared__ float degs[BNODES];
    int t = threadIdx.x;
    degs[t] = 0.f;
    __syncthreads();
    int b = blockIdx.x;
    int bbeg = scn[b * B3];
    int bend = (b + 1 < NB) ? scn[(b + 1) * B3] : E;
    for (int p = bbeg + t; p < bend; p += BNODES) {
        int2 r = payload[p];
        atomicAdd(&degs[(r.x >> 20) & (BNODES - 1)], __int_as_float(r.y));  // LDS f32 atomic
    }
    __syncthreads();
    int node = (b << BSH) + t;
    if (node < N) dis[node] = rsqrtf(1.f + degs[t]);
}

// ---------------- gemm1: h1 = x @ W1, LDS-tiled coalesced ----------------
constexpr int GR  = 256;
constexpr int KT  = 32;
constexpr int LDP = 33;
__global__ __launch_bounds__(256) void gemm1_kernel(const float* __restrict__ x,
                                                    const float* __restrict__ W,
                                                    float* __restrict__ h, int N, int K) {
    __shared__ float tile[GR * LDP];
    int t = threadIdx.x;
    int row0 = blockIdx.x * GR;
    float acc[HID];
#pragma unroll
    for (int j = 0; j < HID; ++j) acc[j] = 0.f;
    for (int kt = 0; kt < K; kt += KT) {
        __syncthreads();
#pragma unroll
        for (int q = 0; q < 8; ++q) {
            int f  = q * 256 + t;
            int r  = f >> 3;
            int c4 = f & 7;
            int gr = row0 + r;
            if (gr > N - 1) gr = N - 1;
            float4 v = *reinterpret_cast<const float4*>(x + (size_t)gr * K + kt + c4 * 4);
            float* dstp = &tile[r * LDP + c4 * 4];
            dstp[0] = v.x; dstp[1] = v.y; dstp[2] = v.z; dstp[3] = v.w;
        }
        __syncthreads();
        const float* Wk = W + (size_t)kt * HID;
        const float* lr = &tile[t * LDP];
#pragma unroll
        for (int k = 0; k < KT; ++k) {
            float a = lr[k];
#pragma unroll
            for (int j = 0; j < HID; ++j)
                acc[j] = fmaf(a, Wk[k * HID + j], acc[j]);
        }
    }
    int row = row0 + t;
    if (row < N) {
        float* hr = h + (size_t)row * HID;
#pragma unroll
        for (int j = 0; j < HID; j += 4)
            *reinterpret_cast<float4*>(hr + j) = make_float4(acc[j], acc[j+1], acc[j+2], acc[j+3]);
    }
}

// ---------------- pull1: per-bucket LDS accumulation, 16 lanes/record ----------------
__global__ __launch_bounds__(TPB) void pull1_kernel(const int2* __restrict__ payload,
        const int* __restrict__ scn, const float* __restrict__ h1,
        const float* __restrict__ dis, const float* __restrict__ b1,
        float* __restrict__ agg1, int E, int N, int NB) {
    __shared__ float acc[BNODES * HID];   // 8 KB
    int t = threadIdx.x;
#pragma unroll
    for (int i = t; i < BNODES * HID; i += TPB) acc[i] = 0.f;
    __syncthreads();
    int b = blockIdx.x;
    int bbeg = scn[b * B3];
    int bend = (b + 1 < NB) ? scn[(b + 1) * B3] : E;
    int rg = t >> 4, j = t & 15;          // 16 records per iteration
    for (int p = bbeg + rg; p < bend; p += TPB / HID) {
        int2 r = payload[p];
        int src = r.x & 0xFFFFF;
        int dl  = (r.x >> 20) & (BNODES - 1);
        float c = dis[src] * __int_as_float(r.y) * h1[(size_t)src * HID + j];
        atomicAdd(&acc[dl * HID + j], c);  // LDS f32 atomic, <=2-way bank alias
    }
    __syncthreads();
    int node0 = b << BSH;
#pragma unroll
    for (int q = 0; q < (BNODES * HID) / TPB; ++q) {
        int idx = q * TPB + t;
        int nl = idx >> 4, jj = idx & 15;
        int node = node0 + nl;
        if (node < N) {
            float d = dis[node];
            agg1[(size_t)node * HID + jj] = b1[jj] + d * (d * h1[(size_t)node * HID + jj] + acc[idx]);
        }
    }
}

// ---------------- gemm2: h2 = relu(agg1) @ W2 ----------------
__global__ void gemm2_kernel(const float* __restrict__ agg1, const float* __restrict__ W2,
                             float* __restrict__ h2, int N) {
    int i = blockIdx.x * TPB + threadIdx.x;
    if (i >= N) return;
    const float* a = agg1 + (size_t)i * HID;
    float hv[HID];
#pragma unroll
    for (int k = 0; k < HID; k += 4) {
        float4 v = *reinterpret_cast<const float4*>(a + k);
        hv[k]     = fmaxf(v.x, 0.f);
        hv[k + 1] = fmaxf(v.y, 0.f);
        hv[k + 2] = fmaxf(v.z, 0.f);
        hv[k + 3] = fmaxf(v.w, 0.f);
    }
    float acc[NC];
#pragma unroll
    for (int c = 0; c < NC; ++c) acc[c] = 0.f;
#pragma unroll
    for (int k = 0; k < HID; ++k)
#pragma unroll
        for (int c = 0; c < NC; ++c)
            acc[c] = fmaf(hv[k], W2[k * NC + c], acc[c]);
    float* o = h2 + (size_t)i * NC;
    *reinterpret_cast<float4*>(o)     = make_float4(acc[0], acc[1], acc[2], acc[3]);
    *reinterpret_cast<float4*>(o + 4) = make_float4(acc[4], acc[5], acc[6], acc[7]);
}

// ---------------- pull2: per-bucket LDS accumulation + fused log_softmax ----------------
__global__ __launch_bounds__(TPB) void pull2_kernel(const int2* __restrict__ payload,
        const int* __restrict__ scn, const float* __restrict__ h2,
        const float* __restrict__ dis, const float* __restrict__ b2,
        float* __restrict__ out, int E, int N, int NB) {
    __shared__ float acc[BNODES * NC];    // 4 KB
    int t = threadIdx.x;
#pragma unroll
    for (int i = t; i < BNODES * NC; i += TPB) acc[i] = 0.f;
    __syncthreads();
    int b = blockIdx.x;
    int bbeg = scn[b * B3];
    int bend = (b + 1 < NB) ? scn[(b + 1) * B3] : E;
    int rg = t >> 3, j = t & 7;           // 32 records per iteration
    for (int p = bbeg + rg; p < bend; p += TPB / NC) {
        int2 r = payload[p];
        int src = r.x & 0xFFFFF;
        int dl  = (r.x >> 20) & (BNODES - 1);
        float c = dis[src] * __int_as_float(r.y) * h2[(size_t)src * NC + j];
        atomicAdd(&acc[dl * NC + j], c);
    }
    __syncthreads();
    int node0 = b << BSH;
    if (t < BNODES) {
        int node = node0 + t;
        if (node < N) {
            float d = dis[node];
            float v[NC];
            float m = -1e30f;
#pragma unroll
            for (int q = 0; q < NC; ++q) {
                v[q] = b2[q] + d * (d * h2[(size_t)node * NC + q] + acc[t * NC + q]);
                m = fmaxf(m, v[q]);
            }
            float s = 0.f;
#pragma unroll
            for (int q = 0; q < NC; ++q) s += __expf(v[q] - m);
            float lse = m + __logf(s);
            float* o = out + (size_t)node * NC;
            *reinterpret_cast<float4*>(o)     = make_float4(v[0]-lse, v[1]-lse, v[2]-lse, v[3]-lse);
            *reinterpret_cast<float4*>(o + 4) = make_float4(v[4]-lse, v[5]-lse, v[6]-lse, v[7]-lse);
        }
    }
}

// ---------------- fallback push-atomic kernels (only if ws too small) ----------------
__global__ void init_deg_kernel(float* deg, int N) {
    int i = blockIdx.x * TPB + threadIdx.x;
    if (i < N) deg[i] = 1.0f;
}
__global__ void deg_edge_kernel(const int* __restrict__ ei, const float* __restrict__ w,
                                float* deg, int E, const int* __restrict__ flag) {
    int e = blockIdx.x * TPB + threadIdx.x;
    if (e >= E) return;
    int is64 = *flag;
    atomAddF(&deg[edge_at(ei, E + e, is64)], w[e]);
}
__global__ void dis_kernel(float* deg, int N) {
    int i = blockIdx.x * TPB + threadIdx.x;
    if (i < N) deg[i] = rsqrtf(deg[i]);
}
__global__ void init_agg1_kernel(const float* __restrict__ h1, const float* __restrict__ dis,
                                 const float* __restrict__ b1, float* __restrict__ agg1, int N) {
    int t = blockIdx.x * TPB + threadIdx.x;
    if (t >= N * HID) return;
    int i = t >> 4, j = t & 15;
    float d = dis[i];
    agg1[t] = b1[j] + d * d * h1[t];
}
__global__ void edge1_kernel(const int* __restrict__ ei, const float* __restrict__ w,
                             const float* __restrict__ dis, const float* __restrict__ h1,
                             float* __restrict__ agg1, int E, const int* __restrict__ flag) {
    int t = blockIdx.x * TPB + threadIdx.x;
    if (t >= E * HID) return;
    int e = t >> 4, j = t & 15;
    int is64 = *flag;
    int src = edge_at(ei, e, is64);
    int dst = edge_at(ei, E + e, is64);
    float nrm = dis[src] * w[e] * dis[dst];
    atomAddF(&agg1[dst * HID + j], nrm * h1[src * HID + j]);
}
__global__ void init_out_kernel(const float* __restrict__ h2, const float* __restrict__ dis,
                                const float* __restrict__ b2, float* __restrict__ out, int N) {
    int t = blockIdx.x * TPB + threadIdx.x;
    if (t >= N * NC) return;
    int i = t >> 3, j = t & 7;
    float d = dis[i];
    out[t] = b2[j] + d * d * h2[t];
}
__global__ void edge2_kernel(const int* __restrict__ ei, const float* __restrict__ w,
                             const float* __restrict__ dis, const float* __restrict__ h2,
                             float* __restrict__ out, int E, const int* __restrict__ flag) {
    int t = blockIdx.x * TPB + threadIdx.x;
    if (t >= E * NC) return;
    int e = t >> 3, j = t & 7;
    int is64 = *flag;
    int src = edge_at(ei, e, is64);
    int dst = edge_at(ei, E + e, is64);
    float nrm = dis[src] * w[e] * dis[dst];
    atomAddF(&out[dst * NC + j], nrm * h2[src * NC + j]);
}
__global__ void lsm_kernel(float* __restrict__ out, int N) {
    int i = blockIdx.x * TPB + threadIdx.x;
    if (i >= N) return;
    float* r = out + (size_t)i * NC;
    float4 a = *reinterpret_cast<const float4*>(r);
    float4 b = *reinterpret_cast<const float4*>(r + 4);
    float v[NC] = {a.x, a.y, a.z, a.w, b.x, b.y, b.z, b.w};
    float m = v[0];
#pragma unroll
    for (int j = 1; j < NC; ++j) m = fmaxf(m, v[j]);
    float s = 0.f;
#pragma unroll
    for (int j = 0; j < NC; ++j) s += expf(v[j] - m);
    float lse = m + logf(s);
#pragma unroll
    for (int j = 0; j < NC; ++j) v[j] -= lse;
    *reinterpret_cast<float4*>(r)     = make_float4(v[0], v[1], v[2], v[3]);
    *reinterpret_cast<float4*>(r + 4) = make_float4(v[4], v[5], v[6], v[7]);
}

extern "C" void kernel_launch(void* const* d_in, const int* in_sizes, int n_in,
                              void* d_out, int out_size, void* d_ws, size_t ws_size,
                              hipStream_t stream) {
    const float* x  = (const float*)d_in[0];
    const int*   ei = (const int*)d_in[1];
    const float* w  = (const float*)d_in[2];
    const float* W1 = (const float*)d_in[3];
    const float* b1 = (const float*)d_in[4];
    const float* W2 = (const float*)d_in[5];
    const float* b2 = (const float*)d_in[6];
    float* out = (float*)d_out;

    int E = in_sizes[2];          // 3,200,000
    int N = out_size / NC;        // 100,000
    int K = in_sizes[0] / N;      // 512

    int NB   = (N + BNODES - 1) >> BSH;   // 782 buckets
    int M    = NB * B3;                   // 200,192 counts
    int nblk = (M + 1023) / 1024;         // 196

    // workspace layout (payload first for 8B alignment)
    int2*  payload = (int2*)d_ws;                    // E
    float* dis  = (float*)(payload + E);             // N
    float* h1   = dis + N;                           // 16N
    float* agg1 = h1 + (size_t)N * HID;              // 16N
    float* h2   = agg1 + (size_t)N * HID;            // 8N
    int*   cnts = (int*)(h2 + (size_t)N * NC);       // M
    int*   bsum = cnts + M;                          // 1024
    int*   flag = bsum + 1024;                       // 1

    size_t need = ((size_t)2 * E + (size_t)N * 41 + M + 1025) * 4;

    auto nb = [](long long n) { return (int)((n + TPB - 1) / TPB); };

    if (ws_size >= need && NB <= NBMAX && nblk <= 1024 && N < (1 << 20)) {
        detect64_kernel<<<1, 64, 0, stream>>>(ei, E, flag);
        p1_count_kernel<<<B3, TPB, 0, stream>>>(ei, cnts, E, NB, flag);
        scan1_kernel<<<nblk, 256, 0, stream>>>(cnts, bsum, M);
        scan2_kernel<<<1, 256, 0, stream>>>(bsum, nblk);
        scan3_kernel<<<nblk, 256, 0, stream>>>(cnts, bsum, M);
        p3_scatter_kernel<<<B3, TPB, 0, stream>>>(ei, w, cnts, payload, E, NB, flag);
        p4_deg_kernel<<<NB, BNODES, 0, stream>>>(payload, cnts, dis, E, N, NB);
        gemm1_kernel<<<(N + GR - 1) / GR, 256, 0, stream>>>(x, W1, h1, N, K);
        pull1_kernel<<<NB, TPB, 0, stream>>>(payload, cnts, h1, dis, b1, agg1, E, N, NB);
        gemm2_kernel<<<nb(N), TPB, 0, stream>>>(agg1, W2, h2, N);
        pull2_kernel<<<NB, TPB, 0, stream>>>(payload, cnts, h2, dis, b2, out, E, N, NB);
    } else {
        // fallback: push atomics (round-1 structure)
        float* deg  = (float*)d_ws;                  // N
        float* fh1  = deg + N;                       // 16N
        float* fagg = fh1 + (size_t)N * HID;         // 16N
        float* fh2  = fagg + (size_t)N * HID;        // 8N
        int*   ffl  = (int*)(fh2 + (size_t)N * NC);  // 1
        detect64_kernel<<<1, 64, 0, stream>>>(ei, E, ffl);
        init_deg_kernel<<<nb(N), TPB, 0, stream>>>(deg, N);
        deg_edge_kernel<<<nb(E), TPB, 0, stream>>>(ei, w, deg, E, ffl);
        dis_kernel<<<nb(N), TPB, 0, stream>>>(deg, N);
        gemm1_kernel<<<(N + GR - 1) / GR, 256, 0, stream>>>(x, W1, fh1, N, K);
        init_agg1_kernel<<<nb((long long)N * HID), TPB, 0, stream>>>(fh1, deg, b1, fagg, N);
        edge1_kernel<<<nb((long long)E * HID), TPB, 0, stream>>>(ei, w, deg, fh1, fagg, E, ffl);
        gemm2_kernel<<<nb(N), TPB, 0, stream>>>(fagg, W2, fh2, N);
        init_out_kernel<<<nb((long long)N * NC), TPB, 0, stream>>>(fh2, deg, b2, out, N);
        edge2_kernel<<<nb((long long)E * NC), TPB, 0, stream>>>(ei, w, deg, fh2, out, E, ffl);
        lsm_kernel<<<nb(N), TPB, 0, stream>>>(out, N);
    }
}

// Round 4
// 913.605 us; speedup vs baseline: 1.1027x; 1.0913x over previous
//
#include <hip/hip_runtime.h>

#define TPB 256
constexpr int HID = 16;
constexpr int NC  = 8;
constexpr int B3  = 256;      // blocks for edge-chunk passes (p1/p3)
constexpr int BSH = 7;        // 128 nodes per bucket
constexpr int BNODES = 128;
constexpr int NBMAX = 1024;   // max buckets (N <= 131072)
constexpr int SSPLIT = 4;     // sub-blocks per bucket in pull/deg passes

__device__ __forceinline__ void atomAddF(float* p, float v) {
    unsafeAtomicAdd(p, v);    // native global_atomic_add_f32
}

// Detect whether edge_index arrived as int64 (odd 32-bit words all zero) or int32.
__global__ void detect64_kernel(const int* __restrict__ ei, int E, int* flag) {
    int l = threadIdx.x;
    int v = 0;
    if (l < 32 && 2 * l + 1 < 2 * E) v = ei[2 * l + 1];
    unsigned long long b = __ballot(v != 0);
    if (l == 0) *flag = (b == 0ULL) ? 1 : 0;
}

__device__ __forceinline__ int edge_at(const int* __restrict__ ei, int index, int is64) {
    return is64 ? ei[2 * index] : ei[index];
}

// ---------------- P1: per-(bucket,block) edge counts via LDS histogram ----------------
__global__ __launch_bounds__(TPB) void p1_count_kernel(const int* __restrict__ ei, int* __restrict__ cnts,
                                                       int E, int NB, const int* __restrict__ flag) {
    __shared__ int h[NBMAX];
    int t = threadIdx.x;
    for (int i = t; i < NB; i += TPB) h[i] = 0;
    __syncthreads();
    int is64 = *flag;
    int chunk = (E + B3 - 1) / B3;
    int beg = blockIdx.x * chunk;
    int end = min(E, beg + chunk);
    for (int e = beg + t; e < end; e += TPB) {
        int dst = edge_at(ei, E + e, is64);
        atomicAdd(&h[dst >> BSH], 1);   // LDS atomic
    }
    __syncthreads();
    for (int i = t; i < NB; i += TPB) cnts[i * B3 + blockIdx.x] = h[i];
}

// ---------------- exclusive scan of M counts ----------------
__global__ void scan1_kernel(const int* __restrict__ a, int* bsum, int M) {
    __shared__ int sd[256];
    int t = threadIdx.x;
    int base = blockIdx.x * 1024 + t * 4;
    int s = 0;
#pragma unroll
    for (int q = 0; q < 4; ++q) if (base + q < M) s += a[base + q];
    sd[t] = s; __syncthreads();
    for (int off = 128; off >= 1; off >>= 1) {
        if (t < off) sd[t] += sd[t + off];
        __syncthreads();
    }
    if (t == 0) bsum[blockIdx.x] = sd[0];
}

__global__ void scan2_kernel(int* bsum, int nb) {
    __shared__ int sd[256];
    int t = threadIdx.x;
    int base = t * 4;
    int v0 = base + 0 < nb ? bsum[base + 0] : 0;
    int v1 = base + 1 < nb ? bsum[base + 1] : 0;
    int v2 = base + 2 < nb ? bsum[base + 2] : 0;
    int v3 = base + 3 < nb ? bsum[base + 3] : 0;
    int s = v0 + v1 + v2 + v3;
    sd[t] = s; __syncthreads();
    for (int off = 1; off < 256; off <<= 1) {
        int val = 0;
        if (t >= off) val = sd[t - off];
        __syncthreads();
        if (t >= off) sd[t] += val;
        __syncthreads();
    }
    int e = sd[t] - s;
    if (base + 0 < nb) bsum[base + 0] = e;           e += v0;
    if (base + 1 < nb) bsum[base + 1] = e;           e += v1;
    if (base + 2 < nb) bsum[base + 2] = e;           e += v2;
    if (base + 3 < nb) bsum[base + 3] = e;
}

__global__ void scan3_kernel(int* a, const int* __restrict__ bsum, int M) {
    __shared__ int sd[256];
    int t = threadIdx.x;
    int base = blockIdx.x * 1024 + t * 4;
    int v0 = 0, v1 = 0, v2 = 0, v3 = 0;
    if (base + 0 < M) v0 = a[base + 0];
    if (base + 1 < M) v1 = a[base + 1];
    if (base + 2 < M) v2 = a[base + 2];
    if (base + 3 < M) v3 = a[base + 3];
    int s = v0 + v1 + v2 + v3;
    sd[t] = s; __syncthreads();
    for (int off = 1; off < 256; off <<= 1) {
        int val = 0;
        if (t >= off) val = sd[t - off];
        __syncthreads();
        if (t >= off) sd[t] += val;
        __syncthreads();
    }
    int excl = sd[t] - s + bsum[blockIdx.x];
    int e0 = excl, e1 = e0 + v0, e2 = e1 + v1, e3 = e2 + v2;
    if (base + 0 < M) a[base + 0] = e0;
    if (base + 1 < M) a[base + 1] = e1;
    if (base + 2 < M) a[base + 2] = e2;
    if (base + 3 < M) a[base + 3] = e3;
}

// ---------------- P3: scatter edges into bucket-major segments (LDS cursors) ----------------
__global__ __launch_bounds__(TPB) void p3_scatter_kernel(const int* __restrict__ ei, const float* __restrict__ w,
                                                         const int* __restrict__ scn, int2* __restrict__ payload,
                                                         int E, int NB, const int* __restrict__ flag) {
    __shared__ int cur[NBMAX];
    int t = threadIdx.x;
    for (int i = t; i < NB; i += TPB) cur[i] = scn[i * B3 + blockIdx.x];
    __syncthreads();
    int is64 = *flag;
    int chunk = (E + B3 - 1) / B3;
    int beg = blockIdx.x * chunk;
    int end = min(E, beg + chunk);
    for (int e = beg + t; e < end; e += TPB) {
        int src = edge_at(ei, e, is64);
        int dst = edge_at(ei, E + e, is64);
        int b = dst >> BSH;
        int p = atomicAdd(&cur[b], 1);   // LDS atomic
        payload[p] = make_int2(src | ((dst & (BNODES - 1)) << 20), __float_as_int(w[e]));
    }
}

// dis = 1.0 (self-loop weight)
__global__ void init_dis_kernel(float* dis, int N) {
    int i = blockIdx.x * TPB + threadIdx.x;
    if (i < N) dis[i] = 1.0f;
}

// ---------------- P4: per-(bucket,sub) weighted degree partials -> global atomics ----------------
__global__ __launch_bounds__(TPB) void p4_deg_kernel(const int2* __restrict__ payload,
                                                     const int* __restrict__ scn,
                                                     float* __restrict__ dis, int E, int N, int NB) {
    __shared__ float degs[BNODES];
    int t = threadIdx.x;
    if (t < BNODES) degs[t] = 0.f;
    __syncthreads();
    int b = blockIdx.x >> 2, s = blockIdx.x & (SSPLIT - 1);
    int bbeg = scn[b * B3];
    int bend = (b + 1 < NB) ? scn[(b + 1) * B3] : E;
    int cntb = bend - bbeg;
    int per  = (cntb + SSPLIT - 1) / SSPLIT;
    int sbeg = bbeg + s * per;
    int send = min(bend, sbeg + per);
    for (int p = sbeg + t; p < send; p += TPB) {
        int2 r = payload[p];
        atomicAdd(&degs[(r.x >> 20) & (BNODES - 1)], __int_as_float(r.y));  // LDS f32
    }
    __syncthreads();
    if (t < BNODES) {
        int node = (b << BSH) + t;
        if (node < N && degs[t] != 0.f) atomAddF(&dis[node], degs[t]);
    }
}

__global__ void rsqrt_kernel(float* dis, int N) {
    int i = blockIdx.x * TPB + threadIdx.x;
    if (i < N) dis[i] = rsqrtf(dis[i]);
}

// ---------------- gemm1: h1' = dis * (x @ W1), LDS-tiled coalesced ----------------
constexpr int GR  = 256;
constexpr int KT  = 32;
constexpr int LDP = 33;
__global__ __launch_bounds__(256) void gemm1_kernel(const float* __restrict__ x,
                                                    const float* __restrict__ W,
                                                    const float* __restrict__ dis,
                                                    float* __restrict__ h, int N, int K) {
    __shared__ float tile[GR * LDP];
    int t = threadIdx.x;
    int row0 = blockIdx.x * GR;
    float acc[HID];
#pragma unroll
    for (int j = 0; j < HID; ++j) acc[j] = 0.f;
    for (int kt = 0; kt < K; kt += KT) {
        __syncthreads();
#pragma unroll
        for (int q = 0; q < 8; ++q) {
            int f  = q * 256 + t;
            int r  = f >> 3;
            int c4 = f & 7;
            int gr = row0 + r;
            if (gr > N - 1) gr = N - 1;
            float4 v = *reinterpret_cast<const float4*>(x + (size_t)gr * K + kt + c4 * 4);
            float* dstp = &tile[r * LDP + c4 * 4];
            dstp[0] = v.x; dstp[1] = v.y; dstp[2] = v.z; dstp[3] = v.w;
        }
        __syncthreads();
        const float* Wk = W + (size_t)kt * HID;
        const float* lr = &tile[t * LDP];
#pragma unroll
        for (int k = 0; k < KT; ++k) {
            float a = lr[k];
#pragma unroll
            for (int j = 0; j < HID; ++j)
                acc[j] = fmaf(a, Wk[k * HID + j], acc[j]);
        }
    }
    int row = row0 + t;
    if (row < N) {
        float d = dis[row];
        float* hr = h + (size_t)row * HID;
#pragma unroll
        for (int j = 0; j < HID; j += 4)
            *reinterpret_cast<float4*>(hr + j) = make_float4(d*acc[j], d*acc[j+1], d*acc[j+2], d*acc[j+3]);
    }
}

// agg1 = b1 + dis * h1'   (self-loop term; pull1 atomically adds the rest)
__global__ void init_agg1_kernel(const float* __restrict__ h1p, const float* __restrict__ dis,
                                 const float* __restrict__ b1, float* __restrict__ agg1, int N) {
    int t = blockIdx.x * TPB + threadIdx.x;
    if (t >= N * HID) return;
    int i = t >> 4, j = t & 15;
    agg1[t] = b1[j] + dis[i] * h1p[t];
}

// ---------------- pull1: per-(bucket,sub) LDS accumulation, 16 lanes/record, 4x unroll ----------------
__global__ __launch_bounds__(TPB) void pull1_kernel(const int2* __restrict__ payload,
        const int* __restrict__ scn, const float* __restrict__ h1p,
        const float* __restrict__ dis, float* __restrict__ agg1, int E, int N, int NB) {
    __shared__ float acc[BNODES * HID];   // 8 KB
    int t = threadIdx.x;
#pragma unroll
    for (int i = t; i < BNODES * HID; i += TPB) acc[i] = 0.f;
    __syncthreads();
    int b = blockIdx.x >> 2, s = blockIdx.x & (SSPLIT - 1);
    int bbeg = scn[b * B3];
    int bend = (b + 1 < NB) ? scn[(b + 1) * B3] : E;
    int cntb = bend - bbeg;
    int per  = (cntb + SSPLIT - 1) / SSPLIT;
    int sbeg = bbeg + s * per;
    int send = min(bend, sbeg + per);
    constexpr int G = TPB / HID;          // 16 records in flight per iter-slot
    int rg = t >> 4, j = t & 15;
    int p = sbeg + rg;
    for (; p + 3 * G < send; p += 4 * G) {
        int2 r0 = payload[p];
        int2 r1 = payload[p + G];
        int2 r2 = payload[p + 2 * G];
        int2 r3 = payload[p + 3 * G];
        float v0 = __int_as_float(r0.y) * h1p[(size_t)(r0.x & 0xFFFFF) * HID + j];
        float v1 = __int_as_float(r1.y) * h1p[(size_t)(r1.x & 0xFFFFF) * HID + j];
        float v2 = __int_as_float(r2.y) * h1p[(size_t)(r2.x & 0xFFFFF) * HID + j];
        float v3 = __int_as_float(r3.y) * h1p[(size_t)(r3.x & 0xFFFFF) * HID + j];
        atomicAdd(&acc[((r0.x >> 20) & (BNODES - 1)) * HID + j], v0);
        atomicAdd(&acc[((r1.x >> 20) & (BNODES - 1)) * HID + j], v1);
        atomicAdd(&acc[((r2.x >> 20) & (BNODES - 1)) * HID + j], v2);
        atomicAdd(&acc[((r3.x >> 20) & (BNODES - 1)) * HID + j], v3);
    }
    for (; p < send; p += G) {
        int2 r = payload[p];
        float v = __int_as_float(r.y) * h1p[(size_t)(r.x & 0xFFFFF) * HID + j];
        atomicAdd(&acc[((r.x >> 20) & (BNODES - 1)) * HID + j], v);
    }
    __syncthreads();
    int node0 = b << BSH;
#pragma unroll
    for (int q = 0; q < (BNODES * HID) / TPB; ++q) {
        int idx = q * TPB + t;
        int nl = idx >> 4, jj = idx & 15;
        int node = node0 + nl;
        if (node < N) {
            float v = acc[idx];
            if (v != 0.f) atomAddF(&agg1[(size_t)node * HID + jj], dis[node] * v);
        }
    }
}

// ---------------- gemm2: h2' = dis * (relu(agg1) @ W2) ----------------
__global__ void gemm2_kernel(const float* __restrict__ agg1, const float* __restrict__ W2,
                             const float* __restrict__ dis, float* __restrict__ h2, int N) {
    int i = blockIdx.x * TPB + threadIdx.x;
    if (i >= N) return;
    const float* a = agg1 + (size_t)i * HID;
    float hv[HID];
#pragma unroll
    for (int k = 0; k < HID; k += 4) {
        float4 v = *reinterpret_cast<const float4*>(a + k);
        hv[k]     = fmaxf(v.x, 0.f);
        hv[k + 1] = fmaxf(v.y, 0.f);
        hv[k + 2] = fmaxf(v.z, 0.f);
        hv[k + 3] = fmaxf(v.w, 0.f);
    }
    float acc[NC];
#pragma unroll
    for (int c = 0; c < NC; ++c) acc[c] = 0.f;
#pragma unroll
    for (int k = 0; k < HID; ++k)
#pragma unroll
        for (int c = 0; c < NC; ++c)
            acc[c] = fmaf(hv[k], W2[k * NC + c], acc[c]);
    float d = dis[i];
    float* o = h2 + (size_t)i * NC;
    *reinterpret_cast<float4*>(o)     = make_float4(d*acc[0], d*acc[1], d*acc[2], d*acc[3]);
    *reinterpret_cast<float4*>(o + 4) = make_float4(d*acc[4], d*acc[5], d*acc[6], d*acc[7]);
}

// out = b2 + dis * h2'  (self-loop; pull2 atomically adds the rest; lsm finishes)
__global__ void init_out_kernel(const float* __restrict__ h2p, const float* __restrict__ dis,
                                const float* __restrict__ b2, float* __restrict__ out, int N) {
    int t = blockIdx.x * TPB + threadIdx.x;
    if (t >= N * NC) return;
    int i = t >> 3, j = t & 7;
    out[t] = b2[j] + dis[i] * h2p[t];
}

// ---------------- pull2: per-(bucket,sub) LDS accumulation, 8 lanes/record, 4x unroll ----------------
__global__ __launch_bounds__(TPB) void pull2_kernel(const int2* __restrict__ payload,
        const int* __restrict__ scn, const float* __restrict__ h2p,
        const float* __restrict__ dis, float* __restrict__ out, int E, int N, int NB) {
    __shared__ float acc[BNODES * NC];    // 4 KB
    int t = threadIdx.x;
#pragma unroll
    for (int i = t; i < BNODES * NC; i += TPB) acc[i] = 0.f;
    __syncthreads();
    int b = blockIdx.x >> 2, s = blockIdx.x & (SSPLIT - 1);
    int bbeg = scn[b * B3];
    int bend = (b + 1 < NB) ? scn[(b + 1) * B3] : E;
    int cntb = bend - bbeg;
    int per  = (cntb + SSPLIT - 1) / SSPLIT;
    int sbeg = bbeg + s * per;
    int send = min(bend, sbeg + per);
    constexpr int G = TPB / NC;           // 32 records in flight per iter-slot
    int rg = t >> 3, j = t & 7;
    int p = sbeg + rg;
    for (; p + 3 * G < send; p += 4 * G) {
        int2 r0 = payload[p];
        int2 r1 = payload[p + G];
        int2 r2 = payload[p + 2 * G];
        int2 r3 = payload[p + 3 * G];
        float v0 = __int_as_float(r0.y) * h2p[(size_t)(r0.x & 0xFFFFF) * NC + j];
        float v1 = __int_as_float(r1.y) * h2p[(size_t)(r1.x & 0xFFFFF) * NC + j];
        float v2 = __int_as_float(r2.y) * h2p[(size_t)(r2.x & 0xFFFFF) * NC + j];
        float v3 = __int_as_float(r3.y) * h2p[(size_t)(r3.x & 0xFFFFF) * NC + j];
        atomicAdd(&acc[((r0.x >> 20) & (BNODES - 1)) * NC + j], v0);
        atomicAdd(&acc[((r1.x >> 20) & (BNODES - 1)) * NC + j], v1);
        atomicAdd(&acc[((r2.x >> 20) & (BNODES - 1)) * NC + j], v2);
        atomicAdd(&acc[((r3.x >> 20) & (BNODES - 1)) * NC + j], v3);
    }
    for (; p < send; p += G) {
        int2 r = payload[p];
        float v = __int_as_float(r.y) * h2p[(size_t)(r.x & 0xFFFFF) * NC + j];
        atomicAdd(&acc[((r.x >> 20) & (BNODES - 1)) * NC + j], v);
    }
    __syncthreads();
    int node0 = b << BSH;
#pragma unroll
    for (int q = 0; q < (BNODES * NC) / TPB; ++q) {
        int idx = q * TPB + t;
        int nl = idx >> 3, jj = idx & 7;
        int node = node0 + nl;
        if (node < N) {
            float v = acc[idx];
            if (v != 0.f) atomAddF(&out[(size_t)node * NC + jj], dis[node] * v);
        }
    }
}

// in-place log_softmax over 8 classes, one row per thread
__global__ void lsm_kernel(float* __restrict__ out, int N) {
    int i = blockIdx.x * TPB + threadIdx.x;
    if (i >= N) return;
    float* r = out + (size_t)i * NC;
    float4 a = *reinterpret_cast<const float4*>(r);
    float4 b = *reinterpret_cast<const float4*>(r + 4);
    float v[NC] = {a.x, a.y, a.z, a.w, b.x, b.y, b.z, b.w};
    float m = v[0];
#pragma unroll
    for (int j = 1; j < NC; ++j) m = fmaxf(m, v[j]);
    float s = 0.f;
#pragma unroll
    for (int j = 0; j < NC; ++j) s += __expf(v[j] - m);
    float lse = m + __logf(s);
#pragma unroll
    for (int j = 0; j < NC; ++j) v[j] -= lse;
    *reinterpret_cast<float4*>(r)     = make_float4(v[0], v[1], v[2], v[3]);
    *reinterpret_cast<float4*>(r + 4) = make_float4(v[4], v[5], v[6], v[7]);
}

// ---------------- fallback push-atomic kernels (only if ws too small) ----------------
__global__ void fb_deg_edge(const int* __restrict__ ei, const float* __restrict__ w,
                            float* deg, int E, const int* __restrict__ flag) {
    int e = blockIdx.x * TPB + threadIdx.x;
    if (e >= E) return;
    int is64 = *flag;
    atomAddF(&deg[edge_at(ei, E + e, is64)], w[e]);
}
__global__ void fb_edge1(const int* __restrict__ ei, const float* __restrict__ w,
                         const float* __restrict__ dis, const float* __restrict__ h1p,
                         float* __restrict__ agg1, int E, const int* __restrict__ flag) {
    int t = blockIdx.x * TPB + threadIdx.x;
    if (t >= E * HID) return;
    int e = t >> 4, j = t & 15;
    int is64 = *flag;
    int src = edge_at(ei, e, is64);
    int dst = edge_at(ei, E + e, is64);
    atomAddF(&agg1[dst * HID + j], w[e] * dis[dst] * h1p[src * HID + j]);
}
__global__ void fb_edge2(const int* __restrict__ ei, const float* __restrict__ w,
                         const float* __restrict__ dis, const float* __restrict__ h2p,
                         float* __restrict__ out, int E, const int* __restrict__ flag) {
    int t = blockIdx.x * TPB + threadIdx.x;
    if (t >= E * NC) return;
    int e = t >> 3, j = t & 7;
    int is64 = *flag;
    int src = edge_at(ei, e, is64);
    int dst = edge_at(ei, E + e, is64);
    atomAddF(&out[dst * NC + j], w[e] * dis[dst] * h2p[src * NC + j]);
}

extern "C" void kernel_launch(void* const* d_in, const int* in_sizes, int n_in,
                              void* d_out, int out_size, void* d_ws, size_t ws_size,
                              hipStream_t stream) {
    const float* x  = (const float*)d_in[0];
    const int*   ei = (const int*)d_in[1];
    const float* w  = (const float*)d_in[2];
    const float* W1 = (const float*)d_in[3];
    const float* b1 = (const float*)d_in[4];
    const float* W2 = (const float*)d_in[5];
    const float* b2 = (const float*)d_in[6];
    float* out = (float*)d_out;

    int E = in_sizes[2];          // 3,200,000
    int N = out_size / NC;        // 100,000
    int K = in_sizes[0] / N;      // 512

    int NB   = (N + BNODES - 1) >> BSH;   // 782 buckets
    int M    = NB * B3;                   // 200,192 counts
    int nblk = (M + 1023) / 1024;         // 196

    // workspace layout (payload first for 8B alignment)
    int2*  payload = (int2*)d_ws;                    // E
    float* dis  = (float*)(payload + E);             // N
    float* h1p  = dis + N;                           // 16N
    float* agg1 = h1p + (size_t)N * HID;             // 16N
    float* h2p  = agg1 + (size_t)N * HID;            // 8N
    int*   cnts = (int*)(h2p + (size_t)N * NC);      // M
    int*   bsum = cnts + M;                          // 1024
    int*   flag = bsum + 1024;                       // 1

    size_t need = ((size_t)2 * E + (size_t)N * 41 + M + 1025) * 4;

    auto nb = [](long long n) { return (int)((n + TPB - 1) / TPB); };

    if (ws_size >= need && NB <= NBMAX && nblk <= 1024 && N < (1 << 20)) {
        detect64_kernel<<<1, 64, 0, stream>>>(ei, E, flag);
        p1_count_kernel<<<B3, TPB, 0, stream>>>(ei, cnts, E, NB, flag);
        scan1_kernel<<<nblk, 256, 0, stream>>>(cnts, bsum, M);
        scan2_kernel<<<1, 256, 0, stream>>>(bsum, nblk);
        scan3_kernel<<<nblk, 256, 0, stream>>>(cnts, bsum, M);
        p3_scatter_kernel<<<B3, TPB, 0, stream>>>(ei, w, cnts, payload, E, NB, flag);
        init_dis_kernel<<<nb(N), TPB, 0, stream>>>(dis, N);
        p4_deg_kernel<<<NB * SSPLIT, TPB, 0, stream>>>(payload, cnts, dis, E, N, NB);
        rsqrt_kernel<<<nb(N), TPB, 0, stream>>>(dis, N);
        gemm1_kernel<<<(N + GR - 1) / GR, 256, 0, stream>>>(x, W1, dis, h1p, N, K);
        init_agg1_kernel<<<nb((long long)N * HID), TPB, 0, stream>>>(h1p, dis, b1, agg1, N);
        pull1_kernel<<<NB * SSPLIT, TPB, 0, stream>>>(payload, cnts, h1p, dis, agg1, E, N, NB);
        gemm2_kernel<<<nb(N), TPB, 0, stream>>>(agg1, W2, dis, h2p, N);
        init_out_kernel<<<nb((long long)N * NC), TPB, 0, stream>>>(h2p, dis, b2, out, N);
        pull2_kernel<<<NB * SSPLIT, TPB, 0, stream>>>(payload, cnts, h2p, dis, out, E, N, NB);
        lsm_kernel<<<nb(N), TPB, 0, stream>>>(out, N);
    } else {
        // fallback: push atomics (round-1 structure, dis folded into h')
        float* fdis = (float*)d_ws;                  // N
        float* fh1  = fdis + N;                      // 16N
        float* fagg = fh1 + (size_t)N * HID;         // 16N
        float* fh2  = fagg + (size_t)N * HID;        // 8N
        int*   ffl  = (int*)(fh2 + (size_t)N * NC);  // 1
        detect64_kernel<<<1, 64, 0, stream>>>(ei, E, ffl);
        init_dis_kernel<<<nb(N), TPB, 0, stream>>>(fdis, N);
        fb_deg_edge<<<nb(E), TPB, 0, stream>>>(ei, w, fdis, E, ffl);
        rsqrt_kernel<<<nb(N), TPB, 0, stream>>>(fdis, N);
        gemm1_kernel<<<(N + GR - 1) / GR, 256, 0, stream>>>(x, W1, fdis, fh1, N, K);
        init_agg1_kernel<<<nb((long long)N * HID), TPB, 0, stream>>>(fh1, fdis, b1, fagg, N);
        fb_edge1<<<nb((long long)E * HID), TPB, 0, stream>>>(ei, w, fdis, fh1, fagg, E, ffl);
        gemm2_kernel<<<nb(N), TPB, 0, stream>>>(fagg, W2, fdis, fh2, N);
        init_out_kernel<<<nb((long long)N * NC), TPB, 0, stream>>>(fh2, fdis, b2, out, N);
        fb_edge2<<<nb((long long)E * NC), TPB, 0, stream>>>(ei, w, fdis, fh2, out, E, ffl);
        lsm_kernel<<<nb(N), TPB, 0, stream>>>(out, N);
    }
}